// Round 5
// baseline (304.739 us; speedup 1.0000x reference)
//
#include <hip/hip_runtime.h>

// MpMaxPoolingMatch: out[b,t,m] = tanh( max_s sum_d lt[b,t,d]*km[m,d]*rt[b,s,d] )
// B=32, T=256, D=512, MP=20.
// R15: R14's phase-pipelined m-loop, spill-proofed. R14 post-mortem: WRITE_SIZE
// 0.64MB -> 152MB + VGPR_Count pinned at 128 = scratch spills from FORCED
// cross-step liveness (xr[2][4] row buffer + hoisted next-km + ring + acc + av
// ~= 200 regs). Fix, per the m131/m141 lesson (don't hand-pipeline against the
// allocator): all staging state is intra-step TRANSIENT -- step u<8 of each
// K-loop loads lt row u + km chunk, converts, ds_writes Anx inline; nothing new
// lives across steps. Live set returns to R13's proven 145 (acc 64 + ring 32 +
// av 32 + addr). Compiler hoists loads where regs are free (optional ILP, not
// mandatory liveness). Runtime 'more' branch removed via compile-time phase
// specialization (4 staging phases + 1 clean final).
// Structure kept from R14: G=5 m/block, grid 512 = 2 blocks/CU resident
// throughout (no ramp/tail); A(m+1) staged under K(m) MFMA (m114 co-schedule);
// B-ring wraps phases (B identical per b); lt working set 2MB/XCD = L2-resident;
// maxbuf parity-dbuf -> ONE barrier per phase. LDS 71.7KB -> 2 blocks/CU.
// cast_rt, rtf layout, MFMA byte order/scales (e8m0=127), epilogue: R13-identical.

constexpr int TT = 256;   // T
constexpr int DD = 512;   // D
constexpr int NM = 20;    // MP
constexpr int NB = 32;    // B
constexpr int BM = 64;    // t-tile
constexpr int GM = 5;     // m-values per block

typedef float f32x4 __attribute__((ext_vector_type(4)));
typedef int   i32x8 __attribute__((ext_vector_type(8)));

struct TrueT  { static constexpr bool value = true;  };
struct FalseT { static constexpr bool value = false; };

__device__ __forceinline__ unsigned pack_bf16(float lo, float hi) {
    unsigned ulo = __builtin_bit_cast(unsigned, lo);
    unsigned uhi = __builtin_bit_cast(unsigned, hi);
    return (ulo >> 16) | (uhi & 0xFFFF0000u);
}

// 4 fp32 -> 4 fp8 (e4m3, packed dword)
__device__ __forceinline__ unsigned pk4_fp8(float a, float b, float c, float d) {
    unsigned r = __builtin_amdgcn_cvt_pk_fp8_f32(a, b, 0, false);
    return __builtin_amdgcn_cvt_pk_fp8_f32(c, d, r, true);
}

// ---------------- Phase 1: rt fp32 -> fp8, 32B-contiguous lane tiles, XCD-aligned ----
// rtf layout: 32B element e = (b*4096 + (kk*16+g)*64 + lane):
//   holds rt[b][s = g*16 + (lane&15)][d = kk*128 + (lane>>4)*32 .. +32] as fp8.
__global__ __launch_bounds__(256)
void cast_rt(const float* __restrict__ rt, unsigned char* __restrict__ rtf)
{
    const int bid = (int)blockIdx.x;       // 0..511
    const int c8  = bid & 7;               // this block's XCD (flat%8)
    const int i   = bid >> 3;              // 0..63
    const int b   = c8 + 8 * (i & 3);      // b%8 == c8 == consumer XCD
    const int sub = i >> 2;                // 0..15
    const int tid = threadIdx.x;
    const int lane = tid & 63;
    const int u6  = sub * 4 + (tid >> 6);  // 0..63 == kk*16 + g
    const int s   = (u6 & 15) * 16 + (lane & 15);
    const int d0  = (u6 >> 4) * 128 + (lane >> 4) * 32;

    const float* p = rt + ((size_t)b * TT + s) * DD + d0;
    float4 x0 = *(const float4*)p;
    float4 x1 = *(const float4*)(p + 4);
    float4 x2 = *(const float4*)(p + 8);
    float4 x3 = *(const float4*)(p + 12);
    float4 x4 = *(const float4*)(p + 16);
    float4 x5 = *(const float4*)(p + 20);
    float4 x6 = *(const float4*)(p + 24);
    float4 x7 = *(const float4*)(p + 28);
    uint4 w0, w1;
    w0.x = pk4_fp8(x0.x, x0.y, x0.z, x0.w);
    w0.y = pk4_fp8(x1.x, x1.y, x1.z, x1.w);
    w0.z = pk4_fp8(x2.x, x2.y, x2.z, x2.w);
    w0.w = pk4_fp8(x3.x, x3.y, x3.z, x3.w);
    w1.x = pk4_fp8(x4.x, x4.y, x4.z, x4.w);
    w1.y = pk4_fp8(x5.x, x5.y, x5.z, x5.w);
    w1.z = pk4_fp8(x6.x, x6.y, x6.z, x6.w);
    w1.w = pk4_fp8(x7.x, x7.y, x7.z, x7.w);
    unsigned char* dst = rtf + ((size_t)b * 4096 + (size_t)u6 * 64 + lane) * 32;
    *(uint4*)dst        = w0;
    *(uint4*)(dst + 16) = w1;
}

// ---------------- Main: 64t x 256s x 5m, MX fp8 K=128, phase-pipelined ----------------
__global__ __launch_bounds__(256, 2)
void mp_match_mx(const float* __restrict__ lt, const unsigned char* __restrict__ rtf,
                 const float* __restrict__ km, float* __restrict__ out)
{
    __shared__ __attribute__((aligned(32))) uint4 Ash[2][BM * 34];   // 69.6 KB dbuf
    __shared__ __attribute__((aligned(16))) float maxbuf[2][4][BM];  // 2 KB dbuf

    // XCD swizzle: flat%8 == XCD; b%8 == XCD.
    const int f  = blockIdx.x;           // 0..511
    const int c8 = f & 7;
    const int i  = f >> 3;               // 0..63
    const int b  = c8 + 8 * (i & 3);     // 0..31
    const int r2 = i >> 2;               // 0..15
    const int mg = r2 & 3;               // m-group: m = mg*5 + mi
    const int t0 = (r2 >> 2) * BM;       // 0,64,128,192

    const int tid  = threadIdx.x;
    const int w    = tid >> 6;           // wave id = s-quarter owner
    const int lane = tid & 63;
    const int l15  = lane & 15;
    const int l4   = lane >> 4;

    const float* ltB = lt + ((size_t)b * TT + t0) * DD;
    // step u: one 32B contiguous load per wave-lane; identical for all phases.
    const unsigned char* rtB0 = rtf + (size_t)b * 131072 + (size_t)(w * 64 + lane) * 32;

    i32x8 ring[4];
    auto loadB = [&](int u) {
        ring[u & 3] = *(const i32x8*)(rtB0 + u * 8192);
    };

    // 3-deep prologue: in flight under the whole first A conversion.
    loadB(0); loadB(1); loadB(2);

    // ---- A-stage helper: thread -> chunk-col cc (d = cc*16..+16), one row.
    const int cc = tid & 31, r0 = (tid >> 5) * 8;
    auto stageRow = [&](int r, const float* kmRow, uint4* dstA) {
        const float* kp  = kmRow + cc * 16;
        const float* src = ltB + (size_t)(r0 + r) * DD + cc * 16;
        float4 k0 = *(const float4*)(kp);
        float4 k1 = *(const float4*)(kp + 4);
        float4 k2 = *(const float4*)(kp + 8);
        float4 k3 = *(const float4*)(kp + 12);
        float4 x0 = *(const float4*)src;
        float4 x1 = *(const float4*)(src + 4);
        float4 x2 = *(const float4*)(src + 8);
        float4 x3 = *(const float4*)(src + 12);
        uint4 o;
        o.x = pk4_fp8(x0.x * k0.x, x0.y * k0.y, x0.z * k0.z, x0.w * k0.w);
        o.y = pk4_fp8(x1.x * k1.x, x1.y * k1.y, x1.z * k1.z, x1.w * k1.w);
        o.z = pk4_fp8(x2.x * k2.x, x2.y * k2.y, x2.z * k2.z, x2.w * k2.w);
        o.w = pk4_fp8(x3.x * k3.x, x3.y * k3.y, x3.z * k3.z, x3.w * k3.w);
        dstA[(r0 + r) * 34 + cc] = o;
    };

    // ---- Prologue A staging (phase 0) into Ash[0].
    {
        const float* km0 = km + (size_t)(mg * GM) * DD;
#pragma unroll
        for (int r = 0; r < 8; ++r) stageRow(r, km0, &Ash[0][0]);
    }
    __syncthreads();

    // ---- One phase: K-loop for m(mi) (+ optional inline staging of m(mi+1)) + epilogue.
    auto phase = [&](int mi, auto STAGE) {
        constexpr bool stg = decltype(STAGE)::value;
        const uint4* Acur = &Ash[mi & 1][0];
        uint4*       Anx  = &Ash[(mi + 1) & 1][0];
        const float* kmn  = km + (size_t)(mg * GM + mi + 1) * DD;  // only deref'd if stg

        f32x4 acc[4][4] = {};   // [ii][q]: t = t0+ii*16+..., s = q*64 + w*16 + ...
        i32x8 av[4];

#pragma unroll
        for (int u = 0; u < 16; ++u) {
            const int kk = u >> 2, q = u & 3;
            // B-ring: wrap next phase's first 3 steps into this phase's tail.
            const int un = u + 3;
            if (un < 16) loadB(un);
            else loadB(un - 16);   // same bytes every phase; harmless in last phase

            if (stg && u < 8) stageRow(u, kmn, Anx);  // intra-step transient staging

            if (q == 0) {
                // A frags for this kk: row = ii*16 + l15, 32B at chunk kk*8 + l4*2.
#pragma unroll
                for (int ii = 0; ii < 4; ++ii)
                    av[ii] = *(const i32x8*)&Acur[(ii * 16 + l15) * 34 + kk * 8 + l4 * 2];
            }
            const i32x8 bv = ring[u & 3];
#pragma unroll
            for (int ii = 0; ii < 4; ++ii)
                acc[ii][q] = __builtin_amdgcn_mfma_scale_f32_16x16x128_f8f6f4(
                    av[ii], bv, acc[ii][q], 0, 0, 0, 127, 0, 127);  // fmt=fp8, scales=1.0
        }

        // ---- Epilogue(m): max over s. C layout: col(s)=lane&15, row(t)=(lane>>4)*4+reg.
        const int m = mg * GM + mi;
#pragma unroll
        for (int ii = 0; ii < 4; ++ii) {
            f32x4 v = acc[ii][0];
#pragma unroll
            for (int q = 1; q < 4; ++q) {
                v.x = fmaxf(v.x, acc[ii][q].x);
                v.y = fmaxf(v.y, acc[ii][q].y);
                v.z = fmaxf(v.z, acc[ii][q].z);
                v.w = fmaxf(v.w, acc[ii][q].w);
            }
#pragma unroll
            for (int off = 1; off < 16; off <<= 1) {
                v.x = fmaxf(v.x, __shfl_xor(v.x, off, 64));
                v.y = fmaxf(v.y, __shfl_xor(v.y, off, 64));
                v.z = fmaxf(v.z, __shfl_xor(v.z, off, 64));
                v.w = fmaxf(v.w, __shfl_xor(v.w, off, 64));
            }
            if (l15 == 0)
                *(f32x4*)&maxbuf[mi & 1][w][ii * 16 + l4 * 4] = v;
        }
        __syncthreads();   // maxbuf(mi) ready; Anx writes drained; Acur reads done
        if (tid < BM) {
            float v = fmaxf(fmaxf(maxbuf[mi & 1][0][tid], maxbuf[mi & 1][1][tid]),
                            fmaxf(maxbuf[mi & 1][2][tid], maxbuf[mi & 1][3][tid]));
            out[((size_t)b * TT + t0 + tid) * NM + m] = tanhf(v);
        }
        // maxbuf WAR across phases handled by parity; next reuse of this parity
        // is separated by the next phase's full barrier.
    };

    for (int mi = 0; mi < GM - 1; ++mi) phase(mi, TrueT{});
    phase(GM - 1, FalseT{});
}

// ---------------- R1 fallback (no workspace): bf16 MFMA, fp32 register staging ----------------
typedef short bf16x8 __attribute__((ext_vector_type(8)));

__global__ __launch_bounds__(256, 2)
void mp_match_kernel(const float* __restrict__ lt, const float* __restrict__ rt,
                     const float* __restrict__ km, float* __restrict__ out)
{
    __shared__ __attribute__((aligned(16))) unsigned short Ash[2][4][128][8];
    __shared__ __attribute__((aligned(16))) unsigned short Bsh2[2][4][256][8];
    __shared__ __attribute__((aligned(16))) float maxbuf[2][128];

    const int ttile = blockIdx.x, m = blockIdx.y, b = blockIdx.z;
    const int t0 = ttile * 128;
    const int tid = threadIdx.x, wave = tid >> 6, lane = tid & 63;
    const int l15 = lane & 15, l4 = lane >> 4;
    const int wt = (wave & 1) * 64, wsi = wave >> 1;

    const float* ltp = lt + ((size_t)b * TT + t0) * DD;
    const float* rtp = rt + (size_t)b * TT * DD;
    const float* kmp = km + (size_t)m * DD;
    const int a_t = tid >> 1, a_h = tid & 1;

    f32x4 acc[4][8] = {};

    auto stage = [&](int kk, int buf) {
        const int d0 = kk * 32;
        const float* ap = ltp + (size_t)a_t * DD + d0 + a_h * 16;
        const float* kp = kmp + d0 + a_h * 16;
#pragma unroll
        for (int q = 0; q < 2; ++q) {
            float4 x0 = *(const float4*)(ap + q * 8);
            float4 x1 = *(const float4*)(ap + q * 8 + 4);
            float4 k0 = *(const float4*)(kp + q * 8);
            float4 k1 = *(const float4*)(kp + q * 8 + 4);
            uint4 wv;
            wv.x = pack_bf16(x0.x * k0.x, x0.y * k0.y);
            wv.y = pack_bf16(x0.z * k0.z, x0.w * k0.w);
            wv.z = pack_bf16(x1.x * k1.x, x1.y * k1.y);
            wv.w = pack_bf16(x1.z * k1.z, x1.w * k1.w);
            *(uint4*)&Ash[buf][a_h * 2 + q][a_t][0] = wv;
        }
        const float* bp = rtp + (size_t)tid * DD + d0;
#pragma unroll
        for (int p = 0; p < 4; ++p) {
            float4 y0 = *(const float4*)(bp + p * 8);
            float4 y1 = *(const float4*)(bp + p * 8 + 4);
            uint4 wv;
            wv.x = pack_bf16(y0.x, y0.y);
            wv.y = pack_bf16(y0.z, y0.w);
            wv.z = pack_bf16(y1.x, y1.y);
            wv.w = pack_bf16(y1.z, y1.w);
            *(uint4*)&Bsh2[buf][p][tid][0] = wv;
        }
    };

    stage(0, 0);
    for (int kk = 0; kk < 16; ++kk) {
        const int buf = kk & 1;
        __syncthreads();
        bf16x8 af[4], bfv[8];
#pragma unroll
        for (int i2 = 0; i2 < 4; ++i2)
            af[i2] = *(const bf16x8*)&Ash[buf][l4][wt + i2 * 16 + l15][0];
#pragma unroll
        for (int j2 = 0; j2 < 8; ++j2)
            bfv[j2] = *(const bf16x8*)&Bsh2[buf][l4][wsi * 128 + j2 * 16 + l15][0];
        if (kk + 1 < 16) stage(kk + 1, buf ^ 1);
#pragma unroll
        for (int i2 = 0; i2 < 4; ++i2)
#pragma unroll
            for (int j2 = 0; j2 < 8; ++j2)
                acc[i2][j2] = __builtin_amdgcn_mfma_f32_16x16x32_bf16(af[i2], bfv[j2], acc[i2][j2], 0, 0, 0);
    }
#pragma unroll
    for (int i2 = 0; i2 < 4; ++i2) {
        f32x4 v = acc[i2][0];
#pragma unroll
        for (int j2 = 1; j2 < 8; ++j2) {
            v.x = fmaxf(v.x, acc[i2][j2].x); v.y = fmaxf(v.y, acc[i2][j2].y);
            v.z = fmaxf(v.z, acc[i2][j2].z); v.w = fmaxf(v.w, acc[i2][j2].w);
        }
#pragma unroll
        for (int off = 1; off < 16; off <<= 1) {
            v.x = fmaxf(v.x, __shfl_xor(v.x, off, 64));
            v.y = fmaxf(v.y, __shfl_xor(v.y, off, 64));
            v.z = fmaxf(v.z, __shfl_xor(v.z, off, 64));
            v.w = fmaxf(v.w, __shfl_xor(v.w, off, 64));
        }
        if (l15 == 0) *(f32x4*)&maxbuf[wsi][wt + i2 * 16 + l4 * 4] = v;
    }
    __syncthreads();
    if (tid < 128) {
        float v = fmaxf(maxbuf[0][tid], maxbuf[1][tid]);
        out[((size_t)b * TT + t0 + tid) * NM + m] = tanhf(v);
    }
}

extern "C" void kernel_launch(void* const* d_in, const int* in_sizes, int n_in,
                              void* d_out, int out_size, void* d_ws, size_t ws_size,
                              hipStream_t stream) {
    const float* lt  = (const float*)d_in[0];   // (32,256,512) fp32
    const float* rt  = (const float*)d_in[1];   // (32,256,512) fp32
    const float* km  = (const float*)d_in[2];   // (20,512) fp32
    float*       out = (float*)d_out;           // (32,256,20) fp32

    const size_t elems = (size_t)NB * TT * DD;  // 4,194,304
    const size_t rtfB  = elems;                 // 4.19 MB fp8 (tiled)

    if (ws_size >= rtfB) {
        unsigned char* rtf = (unsigned char*)d_ws;
        cast_rt<<<512, 256, 0, stream>>>(rt, rtf);           // 32 elem/thread, XCD-aligned
        mp_match_mx<<<512, 256, 0, stream>>>(lt, rtf, km, out);  // 2 blocks/CU, G=5 m-loop
    } else {
        mp_match_kernel<<<dim3(2, NM, NB), 256, 0, stream>>>(lt, rt, km, out);
    }
}

// Round 6
// 132.353 us; speedup vs baseline: 2.3025x; 2.3025x over previous
//
#include <hip/hip_runtime.h>

// MpMaxPoolingMatch: out[b,t,m] = tanh( max_s sum_d lt[b,t,d]*km[m,d]*rt[b,s,d] )
// B=32, T=256, D=512, MP=20.
// R16: R13 minus 16 registers -> 4 waves/SIMD. R14/R15 post-mortem: the m-loop
// never reduced L2 traffic (B/lt re-read per phase either way) and its staging
// liveness spilled (WRITE_SIZE 0.64->162MB). Reverted. The true invariant across
// R10-R13 (all 44-54us, MfmaUtil 15-18%) is 2 waves/SIMD: R13 = 80 arch + 64
// AGPR = 144 unified; occupancy steps at {64,128,256} (m69) -> only total<=128
// helps (-> 4 waves/SIMD). Changes vs R13 (everything else byte-identical):
//  * B-ring 4 -> 2 slots (lead-1): -16 VGPR. Exposes ~200cy L2 latency per step
//    per wave; covered by the DOUBLED TLP (4 waves x ~47% duty saturates the
//    matrix pipe). 2 slots also physically cap in-flight B loads (no hoist-spill).
//  * A-staging re-grained (8-float chunks, 16 rows/thread): peak transients
//    ~48 -> ~20 regs; loads still fully coalesced (64 lanes x 32B/row).
//  * __launch_bounds__(256, 4): allocator budget 512/4 = 128 unified.
// LDS 35.8KB -> 4 blocks/CU (143KB), matching 16 waves/CU.
// MFMA byte order/scales (e8m0=127), Ash stride 34, cast_rt, epilogue: R13-identical.

constexpr int TT = 256;   // T
constexpr int DD = 512;   // D
constexpr int NM = 20;    // MP
constexpr int NB = 32;    // B
constexpr int BM = 64;    // t-tile

typedef float f32x4 __attribute__((ext_vector_type(4)));
typedef int   i32x8 __attribute__((ext_vector_type(8)));

__device__ __forceinline__ unsigned pack_bf16(float lo, float hi) {
    unsigned ulo = __builtin_bit_cast(unsigned, lo);
    unsigned uhi = __builtin_bit_cast(unsigned, hi);
    return (ulo >> 16) | (uhi & 0xFFFF0000u);
}

// 4 fp32 -> 4 fp8 (e4m3, packed dword)
__device__ __forceinline__ unsigned pk4_fp8(float a, float b, float c, float d) {
    unsigned r = __builtin_amdgcn_cvt_pk_fp8_f32(a, b, 0, false);
    return __builtin_amdgcn_cvt_pk_fp8_f32(c, d, r, true);
}

// ---------------- Phase 1: rt fp32 -> fp8, 32B-contiguous lane tiles, XCD-aligned ----
// rtf layout: 32B element e = (b*4096 + (kk*16+g)*64 + lane):
//   holds rt[b][s = g*16 + (lane&15)][d = kk*128 + (lane>>4)*32 .. +32] as fp8.
__global__ __launch_bounds__(256)
void cast_rt(const float* __restrict__ rt, unsigned char* __restrict__ rtf)
{
    const int bid = (int)blockIdx.x;       // 0..511
    const int c8  = bid & 7;               // this block's XCD (flat%8)
    const int i   = bid >> 3;              // 0..63
    const int b   = c8 + 8 * (i & 3);      // b%8 == c8 == consumer XCD
    const int sub = i >> 2;                // 0..15
    const int tid = threadIdx.x;
    const int lane = tid & 63;
    const int u6  = sub * 4 + (tid >> 6);  // 0..63 == kk*16 + g
    const int s   = (u6 & 15) * 16 + (lane & 15);
    const int d0  = (u6 >> 4) * 128 + (lane >> 4) * 32;

    const float* p = rt + ((size_t)b * TT + s) * DD + d0;
    float4 x0 = *(const float4*)p;
    float4 x1 = *(const float4*)(p + 4);
    float4 x2 = *(const float4*)(p + 8);
    float4 x3 = *(const float4*)(p + 12);
    float4 x4 = *(const float4*)(p + 16);
    float4 x5 = *(const float4*)(p + 20);
    float4 x6 = *(const float4*)(p + 24);
    float4 x7 = *(const float4*)(p + 28);
    uint4 w0, w1;
    w0.x = pk4_fp8(x0.x, x0.y, x0.z, x0.w);
    w0.y = pk4_fp8(x1.x, x1.y, x1.z, x1.w);
    w0.z = pk4_fp8(x2.x, x2.y, x2.z, x2.w);
    w0.w = pk4_fp8(x3.x, x3.y, x3.z, x3.w);
    w1.x = pk4_fp8(x4.x, x4.y, x4.z, x4.w);
    w1.y = pk4_fp8(x5.x, x5.y, x5.z, x5.w);
    w1.z = pk4_fp8(x6.x, x6.y, x6.z, x6.w);
    w1.w = pk4_fp8(x7.x, x7.y, x7.z, x7.w);
    unsigned char* dst = rtf + ((size_t)b * 4096 + (size_t)u6 * 64 + lane) * 32;
    *(uint4*)dst        = w0;
    *(uint4*)(dst + 16) = w1;
}

// ---------------- Main: 64t x 256s, MX fp8 K=128, 4 waves/SIMD ----------------
__global__ __launch_bounds__(256, 4)
void mp_match_mx(const float* __restrict__ lt, const unsigned char* __restrict__ rtf,
                 const float* __restrict__ km, float* __restrict__ out)
{
    // stride 34 (even): every A-fragment (2 adjacent uint4) is 32B-aligned.
    __shared__ __attribute__((aligned(32))) uint4 Ash[BM * 34];   // 34.8 KB
    __shared__ __attribute__((aligned(16))) float maxbuf[4][BM];  // 1 KB

    // XCD swizzle: flat%8 == XCD; b%8 == XCD.
    const int f  = blockIdx.x;           // 0..2559
    const int c8 = f & 7;
    const int i  = f >> 3;               // 0..319
    const int b  = c8 + 8 * (i / 80);    // 0..31
    const int j  = i % 80;
    const int m  = j >> 2;               // 0..19
    const int t0 = (j & 3) * BM;         // 0,64,128,192

    const int tid  = threadIdx.x;
    const int w    = tid >> 6;           // wave id = s-quarter owner
    const int lane = tid & 63;
    const int l15  = lane & 15;
    const int l4   = lane >> 4;

    const float* ltB = lt + ((size_t)b * TT + t0) * DD;
    const float* kmp = km + (size_t)m * DD;
    // step u = kk*4+q: one 32B contiguous load per lane at rtB0 + u*8192.
    const unsigned char* rtB0 = rtf + (size_t)b * 131072 + (size_t)(w * 64 + lane) * 32;

    i32x8 ring[2];
    auto loadB = [&](int u) {
        ring[u & 1] = *(const i32x8*)(rtB0 + u * 8192);
    };

    loadB(0);   // in flight under the whole A conversion

    // ---- A staging: thread -> 8-float chunk col cc8 (d = cc8*8..+8), 16 rows.
    // Peak transients ~20 regs (2 km float4 + 2 lt float4 + addr); fully
    // coalesced: 64 lanes x 32B = 2KB contiguous per row per wave.
    {
        const int cc8 = tid & 63;            // 0..63
        const int r0  = (tid >> 6) * 16;     // 16 rows per thread
        const float* kp = kmp + cc8 * 8;
        const float4 k0 = *(const float4*)(kp);
        const float4 k1 = *(const float4*)(kp + 4);
#pragma unroll
        for (int r = 0; r < 16; ++r) {
            const float* src = ltB + (size_t)(r0 + r) * DD + cc8 * 8;
            float4 x0 = *(const float4*)src;
            float4 x1 = *(const float4*)(src + 4);
            uint2 o;
            o.x = pk4_fp8(x0.x * k0.x, x0.y * k0.y, x0.z * k0.z, x0.w * k0.w);
            o.y = pk4_fp8(x1.x * k1.x, x1.y * k1.y, x1.z * k1.z, x1.w * k1.w);
            unsigned* cell = (unsigned*)&Ash[(r0 + r) * 34 + (cc8 >> 1)];
            *(uint2*)(cell + (cc8 & 1) * 2) = o;
        }
    }
    __syncthreads();   // the ONLY pre-epilogue barrier (also drains loadB(0))

    f32x4 acc[4][4] = {};   // [ii][q]: t = t0+ii*16+..., s = q*64 + w*16 + ...
    i32x8 av[4];

#pragma unroll
    for (int u = 0; u < 16; ++u) {
        const int kk = u >> 2, q = u & 3;
        if (u + 1 < 16) loadB(u + 1);   // lead-1; 2-slot ring caps in-flight
        if (q == 0) {
            // A frags for this kk: row = ii*16 + l15, 32B at chunk kk*8 + l4*2.
#pragma unroll
            for (int ii = 0; ii < 4; ++ii)
                av[ii] = *(const i32x8*)&Ash[(ii * 16 + l15) * 34 + kk * 8 + l4 * 2];
        }
        const i32x8 bv = ring[u & 1];
#pragma unroll
        for (int ii = 0; ii < 4; ++ii)
            acc[ii][q] = __builtin_amdgcn_mfma_scale_f32_16x16x128_f8f6f4(
                av[ii], bv, acc[ii][q], 0, 0, 0, 127, 0, 127);  // fmt=fp8, scales=1.0
    }

    // ---- Epilogue: max over s. C layout: col(s)=lane&15, row(t)=(lane>>4)*4+reg.
#pragma unroll
    for (int ii = 0; ii < 4; ++ii) {
        f32x4 v = acc[ii][0];
#pragma unroll
        for (int q = 1; q < 4; ++q) {
            v.x = fmaxf(v.x, acc[ii][q].x);
            v.y = fmaxf(v.y, acc[ii][q].y);
            v.z = fmaxf(v.z, acc[ii][q].z);
            v.w = fmaxf(v.w, acc[ii][q].w);
        }
#pragma unroll
        for (int off = 1; off < 16; off <<= 1) {
            v.x = fmaxf(v.x, __shfl_xor(v.x, off, 64));
            v.y = fmaxf(v.y, __shfl_xor(v.y, off, 64));
            v.z = fmaxf(v.z, __shfl_xor(v.z, off, 64));
            v.w = fmaxf(v.w, __shfl_xor(v.w, off, 64));
        }
        if (l15 == 0)
            *(f32x4*)&maxbuf[w][ii * 16 + l4 * 4] = v;
    }
    __syncthreads();
    if (tid < BM) {
        float v = fmaxf(fmaxf(maxbuf[0][tid], maxbuf[1][tid]),
                        fmaxf(maxbuf[2][tid], maxbuf[3][tid]));
        out[((size_t)b * TT + t0 + tid) * NM + m] = tanhf(v);
    }
}

// ---------------- R1 fallback (no workspace): bf16 MFMA, fp32 register staging ----------------
typedef short bf16x8 __attribute__((ext_vector_type(8)));

__global__ __launch_bounds__(256, 2)
void mp_match_kernel(const float* __restrict__ lt, const float* __restrict__ rt,
                     const float* __restrict__ km, float* __restrict__ out)
{
    __shared__ __attribute__((aligned(16))) unsigned short Ash[2][4][128][8];
    __shared__ __attribute__((aligned(16))) unsigned short Bsh2[2][4][256][8];
    __shared__ __attribute__((aligned(16))) float maxbuf[2][128];

    const int ttile = blockIdx.x, m = blockIdx.y, b = blockIdx.z;
    const int t0 = ttile * 128;
    const int tid = threadIdx.x, wave = tid >> 6, lane = tid & 63;
    const int l15 = lane & 15, l4 = lane >> 4;
    const int wt = (wave & 1) * 64, wsi = wave >> 1;

    const float* ltp = lt + ((size_t)b * TT + t0) * DD;
    const float* rtp = rt + (size_t)b * TT * DD;
    const float* kmp = km + (size_t)m * DD;
    const int a_t = tid >> 1, a_h = tid & 1;

    f32x4 acc[4][8] = {};

    auto stage = [&](int kk, int buf) {
        const int d0 = kk * 32;
        const float* ap = ltp + (size_t)a_t * DD + d0 + a_h * 16;
        const float* kp = kmp + d0 + a_h * 16;
#pragma unroll
        for (int q = 0; q < 2; ++q) {
            float4 x0 = *(const float4*)(ap + q * 8);
            float4 x1 = *(const float4*)(ap + q * 8 + 4);
            float4 k0 = *(const float4*)(kp + q * 8);
            float4 k1 = *(const float4*)(kp + q * 8 + 4);
            uint4 wv;
            wv.x = pack_bf16(x0.x * k0.x, x0.y * k0.y);
            wv.y = pack_bf16(x0.z * k0.z, x0.w * k0.w);
            wv.z = pack_bf16(x1.x * k1.x, x1.y * k1.y);
            wv.w = pack_bf16(x1.z * k1.z, x1.w * k1.w);
            *(uint4*)&Ash[buf][a_h * 2 + q][a_t][0] = wv;
        }
        const float* bp = rtp + (size_t)tid * DD + d0;
#pragma unroll
        for (int p = 0; p < 4; ++p) {
            float4 y0 = *(const float4*)(bp + p * 8);
            float4 y1 = *(const float4*)(bp + p * 8 + 4);
            uint4 wv;
            wv.x = pack_bf16(y0.x, y0.y);
            wv.y = pack_bf16(y0.z, y0.w);
            wv.z = pack_bf16(y1.x, y1.y);
            wv.w = pack_bf16(y1.z, y1.w);
            *(uint4*)&Bsh2[buf][p][tid][0] = wv;
        }
    };

    stage(0, 0);
    for (int kk = 0; kk < 16; ++kk) {
        const int buf = kk & 1;
        __syncthreads();
        bf16x8 af[4], bfv[8];
#pragma unroll
        for (int i2 = 0; i2 < 4; ++i2)
            af[i2] = *(const bf16x8*)&Ash[buf][l4][wt + i2 * 16 + l15][0];
#pragma unroll
        for (int j2 = 0; j2 < 8; ++j2)
            bfv[j2] = *(const bf16x8*)&Bsh2[buf][l4][wsi * 128 + j2 * 16 + l15][0];
        if (kk + 1 < 16) stage(kk + 1, buf ^ 1);
#pragma unroll
        for (int i2 = 0; i2 < 4; ++i2)
#pragma unroll
            for (int j2 = 0; j2 < 8; ++j2)
                acc[i2][j2] = __builtin_amdgcn_mfma_f32_16x16x32_bf16(af[i2], bfv[j2], acc[i2][j2], 0, 0, 0);
    }
#pragma unroll
    for (int i2 = 0; i2 < 4; ++i2) {
        f32x4 v = acc[i2][0];
#pragma unroll
        for (int j2 = 1; j2 < 8; ++j2) {
            v.x = fmaxf(v.x, acc[i2][j2].x); v.y = fmaxf(v.y, acc[i2][j2].y);
            v.z = fmaxf(v.z, acc[i2][j2].z); v.w = fmaxf(v.w, acc[i2][j2].w);
        }
#pragma unroll
        for (int off = 1; off < 16; off <<= 1) {
            v.x = fmaxf(v.x, __shfl_xor(v.x, off, 64));
            v.y = fmaxf(v.y, __shfl_xor(v.y, off, 64));
            v.z = fmaxf(v.z, __shfl_xor(v.z, off, 64));
            v.w = fmaxf(v.w, __shfl_xor(v.w, off, 64));
        }
        if (l15 == 0) *(f32x4*)&maxbuf[wsi][wt + i2 * 16 + l4 * 4] = v;
    }
    __syncthreads();
    if (tid < 128) {
        float v = fmaxf(maxbuf[0][tid], maxbuf[1][tid]);
        out[((size_t)b * TT + t0 + tid) * NM + m] = tanhf(v);
    }
}

extern "C" void kernel_launch(void* const* d_in, const int* in_sizes, int n_in,
                              void* d_out, int out_size, void* d_ws, size_t ws_size,
                              hipStream_t stream) {
    const float* lt  = (const float*)d_in[0];   // (32,256,512) fp32
    const float* rt  = (const float*)d_in[1];   // (32,256,512) fp32
    const float* km  = (const float*)d_in[2];   // (20,512) fp32
    float*       out = (float*)d_out;           // (32,256,20) fp32

    const size_t elems = (size_t)NB * TT * DD;  // 4,194,304
    const size_t rtfB  = elems;                 // 4.19 MB fp8 (tiled)

    if (ws_size >= rtfB) {
        unsigned char* rtf = (unsigned char*)d_ws;
        cast_rt<<<512, 256, 0, stream>>>(rt, rtf);           // 32 elem/thread, XCD-aligned
        mp_match_mx<<<2560, 256, 0, stream>>>(lt, rtf, km, out);
    } else {
        mp_match_kernel<<<dim3(2, NM, NB), 256, 0, stream>>>(lt, rt, km, out);
    }
}

// Round 8
// 112.970 us; speedup vs baseline: 2.6975x; 1.1716x over previous
//
#include <hip/hip_runtime.h>

// MpMaxPoolingMatch: out[b,t,m] = tanh( max_s sum_d lt[b,t,d]*km[m,d]*rt[b,s,d] )
// B=32, T=256, D=512, MP=20.
// R18 == R17 resubmitted (R17's bench died on container acquire, not the kernel;
// bounds/launch audit found no fault path). Rationale recap:
// R17: shrink the per-wave tile, not the register budget. R16 post-mortem:
// forcing 128 regs at the 64t x 64s/wave tile spilled ~32 regs into the K-loop
// (WRITE_SIZE 0.64 -> 82.8MB, dur 47 -> 64us); real need ~150. The register
// floor is acc = per-wave-output/64 lanes, so halve the wave tile:
//  * 512-thread blocks, 8 waves x (64t x 32s); same 64t x 256s block tile,
//    same grid 2560, same total MFMA count (8 steps x 4 MFMA per wave).
//  * acc[4][2]=32 + av 32 + ring[2] 16 + addr ~12 ~= 96-100 unified <= 128
//    -> 4 waves/SIMD SPILL-FREE (launch_bounds(512,4); 28-reg headroom).
//  * 2 blocks/CU (LDS 36.8KB x2), 16 waves/CU. Prologue staging at 2x TLP,
//    8 rows/thread. Per-SIMD: 4 waves x 140cy MFMA bursts tile the timeline;
//    ~420cy slack/wave/step covers the lead-1 L2 B load (~250cy).
// rtf layout, cast_rt, Ash stride 34, MFMA byte order/scales (e8m0=127):
// identical to R13 (bitwise-same operands; only s<->wave grouping changed,
// safe under the max reduction).

constexpr int TT = 256;   // T
constexpr int DD = 512;   // D
constexpr int NM = 20;    // MP
constexpr int NB = 32;    // B
constexpr int BM = 64;    // t-tile

typedef float f32x4 __attribute__((ext_vector_type(4)));
typedef int   i32x8 __attribute__((ext_vector_type(8)));

__device__ __forceinline__ unsigned pack_bf16(float lo, float hi) {
    unsigned ulo = __builtin_bit_cast(unsigned, lo);
    unsigned uhi = __builtin_bit_cast(unsigned, hi);
    return (ulo >> 16) | (uhi & 0xFFFF0000u);
}

// 4 fp32 -> 4 fp8 (e4m3, packed dword)
__device__ __forceinline__ unsigned pk4_fp8(float a, float b, float c, float d) {
    unsigned r = __builtin_amdgcn_cvt_pk_fp8_f32(a, b, 0, false);
    return __builtin_amdgcn_cvt_pk_fp8_f32(c, d, r, true);
}

// ---------------- Phase 1: rt fp32 -> fp8, 32B-contiguous lane tiles, XCD-aligned ----
// rtf layout: 32B element e = (b*4096 + (kk*16+g)*64 + lane):
//   holds rt[b][s = g*16 + (lane&15)][d = kk*128 + (lane>>4)*32 .. +32] as fp8.
__global__ __launch_bounds__(256)
void cast_rt(const float* __restrict__ rt, unsigned char* __restrict__ rtf)
{
    const int bid = (int)blockIdx.x;       // 0..511
    const int c8  = bid & 7;               // this block's XCD (flat%8)
    const int i   = bid >> 3;              // 0..63
    const int b   = c8 + 8 * (i & 3);      // b%8 == c8 == consumer XCD
    const int sub = i >> 2;                // 0..15
    const int tid = threadIdx.x;
    const int lane = tid & 63;
    const int u6  = sub * 4 + (tid >> 6);  // 0..63 == kk*16 + g
    const int s   = (u6 & 15) * 16 + (lane & 15);
    const int d0  = (u6 >> 4) * 128 + (lane >> 4) * 32;

    const float* p = rt + ((size_t)b * TT + s) * DD + d0;
    float4 x0 = *(const float4*)p;
    float4 x1 = *(const float4*)(p + 4);
    float4 x2 = *(const float4*)(p + 8);
    float4 x3 = *(const float4*)(p + 12);
    float4 x4 = *(const float4*)(p + 16);
    float4 x5 = *(const float4*)(p + 20);
    float4 x6 = *(const float4*)(p + 24);
    float4 x7 = *(const float4*)(p + 28);
    uint4 w0, w1;
    w0.x = pk4_fp8(x0.x, x0.y, x0.z, x0.w);
    w0.y = pk4_fp8(x1.x, x1.y, x1.z, x1.w);
    w0.z = pk4_fp8(x2.x, x2.y, x2.z, x2.w);
    w0.w = pk4_fp8(x3.x, x3.y, x3.z, x3.w);
    w1.x = pk4_fp8(x4.x, x4.y, x4.z, x4.w);
    w1.y = pk4_fp8(x5.x, x5.y, x5.z, x5.w);
    w1.z = pk4_fp8(x6.x, x6.y, x6.z, x6.w);
    w1.w = pk4_fp8(x7.x, x7.y, x7.z, x7.w);
    unsigned char* dst = rtf + ((size_t)b * 4096 + (size_t)u6 * 64 + lane) * 32;
    *(uint4*)dst        = w0;
    *(uint4*)(dst + 16) = w1;
}

// ---------------- Main: 8 waves x (64t x 32s), MX fp8 K=128, 4 waves/SIMD ----------------
__global__ __launch_bounds__(512, 4)
void mp_match_mx(const float* __restrict__ lt, const unsigned char* __restrict__ rtf,
                 const float* __restrict__ km, float* __restrict__ out)
{
    // stride 34 (even): every A-fragment (2 adjacent uint4) is 32B-aligned.
    __shared__ __attribute__((aligned(32))) uint4 Ash[BM * 34];   // 34.8 KB
    __shared__ __attribute__((aligned(16))) float maxbuf[8][BM];  // 2 KB

    // XCD swizzle: flat%8 == XCD; b%8 == XCD.
    const int f  = blockIdx.x;           // 0..2559
    const int c8 = f & 7;
    const int i  = f >> 3;               // 0..319
    const int b  = c8 + 8 * (i / 80);    // 0..31
    const int j  = i % 80;
    const int m  = j >> 2;               // 0..19
    const int t0 = (j & 3) * BM;         // 0,64,128,192

    const int tid  = threadIdx.x;        // 0..511
    const int w    = tid >> 6;           // wave id 0..7: owns s = w*32 .. +32
    const int lane = tid & 63;
    const int l15  = lane & 15;
    const int l4   = lane >> 4;

    const float* ltB = lt + ((size_t)b * TT + t0) * DD;
    const float* kmp = km + (size_t)m * DD;
    // step u = kk*2 + jj: B group g = w*2 + jj, s = w*32 + jj*16 + l15.
    // byte = b*131072 + kk*32768 + (w*2+jj)*2048 + lane*32.
    const unsigned char* rtB0 = rtf + (size_t)b * 131072 + (size_t)(w * 128 + lane) * 32;

    i32x8 ring[2];
    auto loadB = [&](int u) {
        ring[u & 1] = *(const i32x8*)(rtB0 + (u >> 1) * 32768 + (u & 1) * 2048);
    };

    loadB(0);   // in flight under the whole A conversion

    // ---- A staging: thread -> 8-float chunk col cc8 (d = cc8*8..+8), 8 rows.
    // 512 threads cover 64 rows x 64 chunks; fully coalesced (2KB/row/wave).
    {
        const int cc8 = tid & 63;            // 0..63
        const int r0  = (tid >> 6) * 8;      // 8 rows per thread
        const float* kp = kmp + cc8 * 8;
        const float4 k0 = *(const float4*)(kp);
        const float4 k1 = *(const float4*)(kp + 4);
#pragma unroll
        for (int r = 0; r < 8; ++r) {
            const float* src = ltB + (size_t)(r0 + r) * DD + cc8 * 8;
            float4 x0 = *(const float4*)src;
            float4 x1 = *(const float4*)(src + 4);
            uint2 o;
            o.x = pk4_fp8(x0.x * k0.x, x0.y * k0.y, x0.z * k0.z, x0.w * k0.w);
            o.y = pk4_fp8(x1.x * k1.x, x1.y * k1.y, x1.z * k1.z, x1.w * k1.w);
            unsigned* cell = (unsigned*)&Ash[(r0 + r) * 34 + (cc8 >> 1)];
            *(uint2*)(cell + (cc8 & 1) * 2) = o;
        }
    }
    __syncthreads();   // the ONLY pre-epilogue barrier (also drains loadB(0))

    f32x4 acc[4][2] = {};   // [ii][jj]: t = t0+ii*16+row, s = w*32 + jj*16 + col
    i32x8 av[4];

#pragma unroll
    for (int u = 0; u < 8; ++u) {
        const int kk = u >> 1, jj = u & 1;
        if (u + 1 < 8) loadB(u + 1);   // lead-1; 2-slot ring caps in-flight
        if (jj == 0) {
            // A frags for this kk: row = ii*16 + l15, 32B at chunk kk*8 + l4*2.
#pragma unroll
            for (int ii = 0; ii < 4; ++ii)
                av[ii] = *(const i32x8*)&Ash[(ii * 16 + l15) * 34 + kk * 8 + l4 * 2];
        }
        const i32x8 bv = ring[u & 1];
#pragma unroll
        for (int ii = 0; ii < 4; ++ii)
            acc[ii][jj] = __builtin_amdgcn_mfma_scale_f32_16x16x128_f8f6f4(
                av[ii], bv, acc[ii][jj], 0, 0, 0, 127, 0, 127);  // fmt=fp8, scales=1.0
    }

    // ---- Epilogue: max over s. C layout: col(s)=lane&15, row(t)=(lane>>4)*4+reg.
#pragma unroll
    for (int ii = 0; ii < 4; ++ii) {
        f32x4 v = acc[ii][0];
        v.x = fmaxf(v.x, acc[ii][1].x);
        v.y = fmaxf(v.y, acc[ii][1].y);
        v.z = fmaxf(v.z, acc[ii][1].z);
        v.w = fmaxf(v.w, acc[ii][1].w);
#pragma unroll
        for (int off = 1; off < 16; off <<= 1) {
            v.x = fmaxf(v.x, __shfl_xor(v.x, off, 64));
            v.y = fmaxf(v.y, __shfl_xor(v.y, off, 64));
            v.z = fmaxf(v.z, __shfl_xor(v.z, off, 64));
            v.w = fmaxf(v.w, __shfl_xor(v.w, off, 64));
        }
        if (l15 == 0)
            *(f32x4*)&maxbuf[w][ii * 16 + l4 * 4] = v;
    }
    __syncthreads();
    if (tid < BM) {
        float v0 = fmaxf(fmaxf(maxbuf[0][tid], maxbuf[1][tid]),
                         fmaxf(maxbuf[2][tid], maxbuf[3][tid]));
        float v1 = fmaxf(fmaxf(maxbuf[4][tid], maxbuf[5][tid]),
                         fmaxf(maxbuf[6][tid], maxbuf[7][tid]));
        out[((size_t)b * TT + t0 + tid) * NM + m] = tanhf(fmaxf(v0, v1));
    }
}

// ---------------- R1 fallback (no workspace): bf16 MFMA, fp32 register staging ----------------
typedef short bf16x8 __attribute__((ext_vector_type(8)));

__global__ __launch_bounds__(256, 2)
void mp_match_kernel(const float* __restrict__ lt, const float* __restrict__ rt,
                     const float* __restrict__ km, float* __restrict__ out)
{
    __shared__ __attribute__((aligned(16))) unsigned short Ash[2][4][128][8];
    __shared__ __attribute__((aligned(16))) unsigned short Bsh2[2][4][256][8];
    __shared__ __attribute__((aligned(16))) float maxbuf[2][128];

    const int ttile = blockIdx.x, m = blockIdx.y, b = blockIdx.z;
    const int t0 = ttile * 128;
    const int tid = threadIdx.x, wave = tid >> 6, lane = tid & 63;
    const int l15 = lane & 15, l4 = lane >> 4;
    const int wt = (wave & 1) * 64, wsi = wave >> 1;

    const float* ltp = lt + ((size_t)b * TT + t0) * DD;
    const float* rtp = rt + (size_t)b * TT * DD;
    const float* kmp = km + (size_t)m * DD;
    const int a_t = tid >> 1, a_h = tid & 1;

    f32x4 acc[4][8] = {};

    auto stage = [&](int kk, int buf) {
        const int d0 = kk * 32;
        const float* ap = ltp + (size_t)a_t * DD + d0 + a_h * 16;
        const float* kp = kmp + d0 + a_h * 16;
#pragma unroll
        for (int q = 0; q < 2; ++q) {
            float4 x0 = *(const float4*)(ap + q * 8);
            float4 x1 = *(const float4*)(ap + q * 8 + 4);
            float4 k0 = *(const float4*)(kp + q * 8);
            float4 k1 = *(const float4*)(kp + q * 8 + 4);
            uint4 wv;
            wv.x = pack_bf16(x0.x * k0.x, x0.y * k0.y);
            wv.y = pack_bf16(x0.z * k0.z, x0.w * k0.w);
            wv.z = pack_bf16(x1.x * k1.x, x1.y * k1.y);
            wv.w = pack_bf16(x1.z * k1.z, x1.w * k1.w);
            *(uint4*)&Ash[buf][a_h * 2 + q][a_t][0] = wv;
        }
        const float* bp = rtp + (size_t)tid * DD + d0;
#pragma unroll
        for (int p = 0; p < 4; ++p) {
            float4 y0 = *(const float4*)(bp + p * 8);
            float4 y1 = *(const float4*)(bp + p * 8 + 4);
            uint4 wv;
            wv.x = pack_bf16(y0.x, y0.y);
            wv.y = pack_bf16(y0.z, y0.w);
            wv.z = pack_bf16(y1.x, y1.y);
            wv.w = pack_bf16(y1.z, y1.w);
            *(uint4*)&Bsh2[buf][p][tid][0] = wv;
        }
    };

    stage(0, 0);
    for (int kk = 0; kk < 16; ++kk) {
        const int buf = kk & 1;
        __syncthreads();
        bf16x8 af[4], bfv[8];
#pragma unroll
        for (int i2 = 0; i2 < 4; ++i2)
            af[i2] = *(const bf16x8*)&Ash[buf][l4][wt + i2 * 16 + l15][0];
#pragma unroll
        for (int j2 = 0; j2 < 8; ++j2)
            bfv[j2] = *(const bf16x8*)&Bsh2[buf][l4][wsi * 128 + j2 * 16 + l15][0];
        if (kk + 1 < 16) stage(kk + 1, buf ^ 1);
#pragma unroll
        for (int i2 = 0; i2 < 4; ++i2)
#pragma unroll
            for (int j2 = 0; j2 < 8; ++j2)
                acc[i2][j2] = __builtin_amdgcn_mfma_f32_16x16x32_bf16(af[i2], bfv[j2], acc[i2][j2], 0, 0, 0);
    }
#pragma unroll
    for (int i2 = 0; i2 < 4; ++i2) {
        f32x4 v = acc[i2][0];
#pragma unroll
        for (int j2 = 1; j2 < 8; ++j2) {
            v.x = fmaxf(v.x, acc[i2][j2].x); v.y = fmaxf(v.y, acc[i2][j2].y);
            v.z = fmaxf(v.z, acc[i2][j2].z); v.w = fmaxf(v.w, acc[i2][j2].w);
        }
#pragma unroll
        for (int off = 1; off < 16; off <<= 1) {
            v.x = fmaxf(v.x, __shfl_xor(v.x, off, 64));
            v.y = fmaxf(v.y, __shfl_xor(v.y, off, 64));
            v.z = fmaxf(v.z, __shfl_xor(v.z, off, 64));
            v.w = fmaxf(v.w, __shfl_xor(v.w, off, 64));
        }
        if (l15 == 0) *(f32x4*)&maxbuf[wsi][wt + i2 * 16 + l4 * 4] = v;
    }
    __syncthreads();
    if (tid < 128) {
        float v = fmaxf(maxbuf[0][tid], maxbuf[1][tid]);
        out[((size_t)b * TT + t0 + tid) * NM + m] = tanhf(v);
    }
}

extern "C" void kernel_launch(void* const* d_in, const int* in_sizes, int n_in,
                              void* d_out, int out_size, void* d_ws, size_t ws_size,
                              hipStream_t stream) {
    const float* lt  = (const float*)d_in[0];   // (32,256,512) fp32
    const float* rt  = (const float*)d_in[1];   // (32,256,512) fp32
    const float* km  = (const float*)d_in[2];   // (20,512) fp32
    float*       out = (float*)d_out;           // (32,256,20) fp32

    const size_t elems = (size_t)NB * TT * DD;  // 4,194,304
    const size_t rtfB  = elems;                 // 4.19 MB fp8 (tiled)

    if (ws_size >= rtfB) {
        unsigned char* rtf = (unsigned char*)d_ws;
        cast_rt<<<512, 256, 0, stream>>>(rt, rtf);           // 32 elem/thread, XCD-aligned
        mp_match_mx<<<2560, 512, 0, stream>>>(lt, rtf, km, out);  // 8 waves x 64t x 32s
    } else {
        mp_match_kernel<<<dim3(2, NM, NB), 256, 0, stream>>>(lt, rt, km, out);
    }
}